// Round 2
// baseline (337.161 us; speedup 1.0000x reference)
//
#include <hip/hip_runtime.h>
#include <hip/hip_bf16.h>
#include <cmath>

#pragma clang fp contract(off)

#define NT 256
constexpr int B_ = 256, Q_ = 300, C_ = 81, V_ = 117, K_ = 100;
constexpr int QC_ = Q_ * C_;   // 24300
constexpr int KV_ = K_ * V_;   // 11700
constexpr int NBIN = 8192;     // histogram bins on float bits >> 19
constexpr int CAP  = 4096;     // candidate buffer capacity

__device__ __forceinline__ unsigned long long shfl_xor_u64(unsigned long long v, int mask) {
    unsigned int lo = (unsigned int)v, hi = (unsigned int)(v >> 32);
    lo = (unsigned int)__shfl_xor((int)lo, mask, 64);
    hi = (unsigned int)__shfl_xor((int)hi, mask, 64);
    return ((unsigned long long)hi << 32) | lo;
}

__device__ __forceinline__ float iou1(const float* a, const float* b) {
    float areaA = (a[2] - a[0] + 1.f) * (a[3] - a[1] + 1.f);
    float areaB = (b[2] - b[0] + 1.f) * (b[3] - b[1] + 1.f);
    float xx1 = fmaxf(a[0], b[0]);
    float yy1 = fmaxf(a[1], b[1]);
    float xx2 = fminf(a[2], b[2]);
    float yy2 = fminf(a[3], b[3]);
    float w = fmaxf(0.f, xx2 - xx1 + 1.f);
    float h = fmaxf(0.f, yy2 - yy1 + 1.f);
    float inter = w * h;
    return inter / (areaA + areaB - inter);
}

__global__ __launch_bounds__(NT) void hoi_kernel(
    const float* __restrict__ obj_logits,   // B,Q,C
    const float* __restrict__ verb_logits,  // B,Q,V
    const float* __restrict__ sub_boxes_in, // B,Q,4
    const float* __restrict__ obj_boxes_in, // B,Q,4
    const float* __restrict__ cm,           // V,C
    const int*   __restrict__ tsizes,       // B,2 (h,w)
    float* __restrict__ out)
{
    const int b = blockIdx.x;
    const int tid = threadIdx.x;

    // big union buffer: phases 1-5 = [rowmax|rowsum|hist/cand], phase 6+ = hs[KV_]
    __shared__ __align__(16) unsigned char sbuf[KV_ * 4];            // 46800 B
    float* rowmax = (float*)sbuf;                                    // [304]
    float* rowsum = (float*)(sbuf + 1216);                           // [304]
    unsigned int* hist = (unsigned int*)(sbuf + 2432);               // [8192]
    unsigned long long* cand = (unsigned long long*)(sbuf + 2432);   // [4096]
    float* hs = (float*)sbuf;                                        // [11700]

    __shared__ float sel_val[K_];
    __shared__ int   sel_q[K_], sel_lab[K_];
    __shared__ float bsub[K_][4], bobj[K_][4];
    __shared__ int   maxbits[K_], order_[K_], keep_un[K_], sup[K_];
    __shared__ unsigned int csum[NT];
    __shared__ unsigned long long wred[4];
    __shared__ unsigned long long s_key;
    __shared__ int sT, s_cur;
    __shared__ unsigned int s_cnt;

    const float* lg = obj_logits + (size_t)b * QC_;

    // ---- Phase 1: per-row max & sum(exp). 8 groups of 32 lanes. ----
    {
        int g = tid >> 5, l = tid & 31;
        for (int q = g; q < Q_; q += 8) {
            float m = -INFINITY;
            for (int c = l; c < C_; c += 32) m = fmaxf(m, lg[q * C_ + c]);
            for (int off = 16; off > 0; off >>= 1) m = fmaxf(m, __shfl_xor(m, off, 64));
            float s = 0.f;
            for (int c = l; c < C_; c += 32) s += expf(lg[q * C_ + c] - m);
            for (int off = 16; off > 0; off >>= 1) s += __shfl_xor(s, off, 64);
            if (l == 0) { rowmax[q] = m; rowsum[q] = s; }
        }
    }
    for (int i = tid; i < NBIN; i += NT) hist[i] = 0;
    if (tid == 0) s_cnt = 0;
    __syncthreads();

    // ---- Phase 2: histogram of prob float-bits ----
    for (int i = tid; i < QC_; i += NT) {
        int q = (int)((unsigned)i / (unsigned)C_);
        float p = expf(lg[i] - rowmax[q]) / rowsum[q];
        atomicAdd(&hist[__float_as_uint(p) >> 19], 1u);
    }
    __syncthreads();

    // ---- Phase 3: find threshold bin T: count(bins > T) < 100 <= count(bins >= T) ----
    {
        unsigned s = 0;
        int base = tid * (NBIN / NT);
        for (int k = 0; k < NBIN / NT; k++) s += hist[base + k];
        csum[tid] = s;
    }
    __syncthreads();
    if (tid == 0) {
        unsigned acc = 0; int T = 0;
        for (int t = NT - 1; t >= 0; t--) {
            if (acc + csum[t] >= (unsigned)K_) {
                int base = t * (NBIN / NT);
                for (int bn = base + NBIN / NT - 1; bn >= base; bn--) {
                    unsigned h = hist[bn];
                    if (acc + h >= (unsigned)K_) { T = bn; break; }
                    acc += h;
                }
                break;
            }
            acc += csum[t];
        }
        sT = T;
    }
    __syncthreads();
    const int T = sT;
    __syncthreads();   // everyone has T; hist region may now be reused as cand

    // ---- Phase 4: collect candidates (bin >= T) as (bits<<32)|~i keys ----
    for (int i = tid; i < QC_; i += NT) {
        int q = (int)((unsigned)i / (unsigned)C_);
        float p = expf(lg[i] - rowmax[q]) / rowsum[q];
        unsigned bits = __float_as_uint(p);
        if ((int)(bits >> 19) >= T) {
            unsigned pos = atomicAdd(&s_cnt, 1u);
            if (pos < (unsigned)CAP)
                cand[pos] = ((unsigned long long)bits << 32) | (unsigned)(~i);
        }
    }
    __syncthreads();
    const int ncand = (int)min(s_cnt, (unsigned)CAP);

    // ---- Phase 5: top-100 by iterative block argmax (exact lax.top_k tie semantics) ----
    for (int r = 0; r < K_; r++) {
        unsigned long long local = 0;
        for (int i = tid; i < ncand; i += NT) {
            unsigned long long v = cand[i];
            if (v > local) local = v;
        }
        for (int off = 32; off > 0; off >>= 1) {
            unsigned long long o = shfl_xor_u64(local, off);
            if (o > local) local = o;
        }
        if ((tid & 63) == 0) wred[tid >> 6] = local;
        __syncthreads();
        if (tid == 0) {
            unsigned long long m = wred[0];
            for (int wv = 1; wv < 4; wv++) if (wred[wv] > m) m = wred[wv];
            s_key = m;
            unsigned idx = ~(unsigned)(m & 0xFFFFFFFFull);
            if (idx >= (unsigned)QC_) idx = 0;  // degenerate-safety
            sel_val[r] = __uint_as_float((unsigned)(m >> 32));
            sel_q[r]   = (int)(idx / (unsigned)C_);
            sel_lab[r] = (int)(idx % (unsigned)C_);
        }
        __syncthreads();
        unsigned long long key = s_key;
        for (int i = tid; i < ncand; i += NT)
            if (cand[i] == key) cand[i] = 0;
        __syncthreads();
    }

    // ---- Phase 5.5: gather + scale boxes; init NMS state ----
    if (tid < K_) {
        int r = tid;
        int q = sel_q[r];
        float iw = (float)tsizes[b * 2 + 1];
        float ih = (float)tsizes[b * 2 + 0];
        const float* sb = sub_boxes_in + ((size_t)b * Q_ + q) * 4;
        const float* ob = obj_boxes_in + ((size_t)b * Q_ + q) * 4;
        float cx = sb[0], cy = sb[1], bw = sb[2], bh = sb[3];
        bsub[r][0] = (cx - 0.5f * bw) * iw; bsub[r][1] = (cy - 0.5f * bh) * ih;
        bsub[r][2] = (cx + 0.5f * bw) * iw; bsub[r][3] = (cy + 0.5f * bh) * ih;
        cx = ob[0]; cy = ob[1]; bw = ob[2]; bh = ob[3];
        bobj[r][0] = (cx - 0.5f * bw) * iw; bobj[r][1] = (cy - 0.5f * bh) * ih;
        bobj[r][2] = (cx + 0.5f * bw) * iw; bobj[r][3] = (cy + 0.5f * bh) * ih;
        maxbits[r] = 0;
        sup[r] = 0;
    }
    __syncthreads();

    // ---- Phase 6: hoi scores (sigmoid * topk_val * mask) into hs (reuses sbuf) ----
    for (int f = tid; f < KV_; f += NT) {
        int r = f / V_, v = f - r * V_;
        int q = sel_q[r];
        float x = verb_logits[((size_t)b * Q_ + q) * V_ + v];
        float s = 1.f / (1.f + expf(-x));
        float hval = s * sel_val[r] * cm[v * C_ + sel_lab[r]];
        hs[f] = hval;
        atomicMax(&maxbits[r], __float_as_int(hval));   // hval >= 0: int-bits monotone
    }
    __syncthreads();

    // ---- Phase 7: stable descending order of max scores (rank-based) ----
    if (tid < K_) {
        int r = tid;
        unsigned long long kr = ((unsigned long long)(unsigned)maxbits[r] << 32) | (unsigned)(~r);
        int rank = 0;
        for (int j = 0; j < K_; j++) {
            unsigned long long kj = ((unsigned long long)(unsigned)maxbits[j] << 32) | (unsigned)(~j);
            rank += (kj > kr) ? 1 : 0;
        }
        order_[rank] = r;
    }
    __syncthreads();

    // ---- Phase 8: greedy NMS in sorted space ----
    for (int i = 0; i < K_; i++) {
        __syncthreads();
        if (tid == 0) {
            int ki = sup[i] ? 0 : 1;
            s_cur = ki;
            keep_un[order_[i]] = ki;
        }
        __syncthreads();
        if (s_cur) {
            int ri = order_[i];
            for (int j = i + 1 + tid; j < K_; j += NT) {
                int rj = order_[j];
                if (sel_lab[ri] == sel_lab[rj]) {
                    float o = iou1(bsub[ri], bsub[rj]) * iou1(bobj[ri], bobj[rj]);
                    if (o > 0.5f) sup[j] = 1;
                }
            }
        }
    }
    __syncthreads();

    // ---- Phase 9: write all outputs (float32, concatenated in return order) ----
    float* o0 = out;                                   // final_scores B,K,V
    float* o1 = out + (size_t)B_ * KV_;                // topk_values  B,K
    float* o2 = o1 + (size_t)B_ * K_;                  // obj_labels   B,K
    float* o3 = o2 + (size_t)B_ * K_;                  // sub_boxes    B,K,4
    float* o4 = o3 + (size_t)B_ * K_ * 4;              // obj_boxes    B,K,4
    float* o5 = o4 + (size_t)B_ * K_ * 4;              // keep         B,K

    for (int f = tid; f < KV_; f += NT) {
        int r = f / V_;
        float v = keep_un[r] ? hs[f] : 0.f;
        o0[(size_t)b * KV_ + f] = v;
    }
    if (tid < K_) {
        int r = tid;
        o1[(size_t)b * K_ + r] = sel_val[r];
        o2[(size_t)b * K_ + r] = (float)sel_lab[r];
        o5[(size_t)b * K_ + r] = keep_un[r] ? 1.f : 0.f;
    }
    for (int f = tid; f < K_ * 4; f += NT) {
        int r = f >> 2, k = f & 3;
        o3[((size_t)b * K_) * 4 + f] = bsub[r][k];
        o4[((size_t)b * K_) * 4 + f] = bobj[r][k];
    }
}

extern "C" void kernel_launch(void* const* d_in, const int* in_sizes, int n_in,
                              void* d_out, int out_size, void* d_ws, size_t ws_size,
                              hipStream_t stream) {
    const float* obj_logits  = (const float*)d_in[0];
    const float* verb_logits = (const float*)d_in[1];
    const float* sub_boxes   = (const float*)d_in[2];
    const float* obj_boxes   = (const float*)d_in[3];
    const float* cm          = (const float*)d_in[4];
    const int*   ts          = (const int*)d_in[5];
    hipLaunchKernelGGL(hoi_kernel, dim3(B_), dim3(NT), 0, stream,
                       obj_logits, verb_logits, sub_boxes, obj_boxes, cm, ts,
                       (float*)d_out);
}

// Round 3
// 161.230 us; speedup vs baseline: 2.0912x; 2.0912x over previous
//
#include <hip/hip_runtime.h>
#include <cmath>

#pragma clang fp contract(off)

#define NT 1024
constexpr int B_ = 256, Q_ = 300, C_ = 81, V_ = 117, K_ = 100;
constexpr int QC_ = Q_ * C_;   // 24300
constexpr int KV_ = K_ * V_;   // 11700
constexpr int NBIN = 8192;     // histogram bins on prob float-bits >> 19
constexpr int CAP  = 1024;     // candidate buffer == bitonic sort size

using u32 = unsigned int;
using u64 = unsigned long long;

__device__ __forceinline__ u64 shfl_xor_u64(u64 v, int mask) {
    u32 lo = (u32)v, hi = (u32)(v >> 32);
    lo = (u32)__shfl_xor((int)lo, mask, 64);
    hi = (u32)__shfl_xor((int)hi, mask, 64);
    return ((u64)hi << 32) | lo;
}

__device__ __forceinline__ float iou1(const float* a, const float* b) {
    float areaA = (a[2] - a[0] + 1.f) * (a[3] - a[1] + 1.f);
    float areaB = (b[2] - b[0] + 1.f) * (b[3] - b[1] + 1.f);
    float xx1 = fmaxf(a[0], b[0]);
    float yy1 = fmaxf(a[1], b[1]);
    float xx2 = fminf(a[2], b[2]);
    float yy2 = fminf(a[3], b[3]);
    float w = fmaxf(0.f, xx2 - xx1 + 1.f);
    float h = fmaxf(0.f, yy2 - yy1 + 1.f);
    float inter = w * h;
    return inter / (areaA + areaB - inter);
}

__global__ __launch_bounds__(NT) void hoi_kernel(
    const float* __restrict__ obj_logits,   // B,Q,C
    const float* __restrict__ verb_logits,  // B,Q,V
    const float* __restrict__ sub_boxes_in, // B,Q,4
    const float* __restrict__ obj_boxes_in, // B,Q,4
    const float* __restrict__ cm,           // V,C
    const int*   __restrict__ tsizes,       // B,2 (h,w)
    float* __restrict__ out)
{
    const int b = blockIdx.x;
    const int tid = threadIdx.x;

    // union buffer: [rowmax|rowsum|hist(alias cand)|csum] early, hs[KV_] late
    __shared__ __align__(16) unsigned char sbuf[KV_ * 4];          // 46800 B
    float* rowmax = (float*)sbuf;                                  // [304] f32
    float* rowsum = (float*)(sbuf + 1216);                         // [304] f32
    u32*   hist   = (u32*)(sbuf + 2432);                           // [8192] ends 35200
    u64*   cand   = (u64*)(sbuf + 2432);                           // [1024] ends 10624 (aliases hist)
    u32*   csum   = (u32*)(sbuf + 35200);                          // [1024] ends 39296
    float* hs     = (float*)sbuf;                                  // [11700]

    __shared__ float sel_val[K_];
    __shared__ int   sel_q[K_], sel_lab[K_];
    __shared__ float bsub[K_][4], bobj[K_][4];
    __shared__ int   maxbits[K_], order_[K_], keep_un[K_];
    __shared__ u32   suprow[K_][4];        // 100x128-bit suppression matrix (sorted space)
    __shared__ u32   skeep[4];
    __shared__ u32   swsum[16];
    __shared__ u64   wred[16];
    __shared__ u64   s_prev;
    __shared__ int   sT;
    __shared__ u32   s_cnt;

    const float* lg = obj_logits + (size_t)b * QC_;

    // ---- Phase 1: per-row max & sum(exp). 32 groups of 32 lanes. ----
    {
        int g = tid >> 5, l = tid & 31;
        for (int q = g; q < Q_; q += 32) {
            float m = -INFINITY;
            for (int c = l; c < C_; c += 32) m = fmaxf(m, lg[q * C_ + c]);
            for (int off = 16; off > 0; off >>= 1) m = fmaxf(m, __shfl_xor(m, off, 64));
            float s = 0.f;
            for (int c = l; c < C_; c += 32) s += expf(lg[q * C_ + c] - m);
            for (int off = 16; off > 0; off >>= 1) s += __shfl_xor(s, off, 64);
            if (l == 0) { rowmax[q] = m; rowsum[q] = s; }
        }
    }
    for (int i = tid; i < NBIN; i += NT) hist[i] = 0;
    if (tid == 0) s_cnt = 0;
    __syncthreads();

    // ---- Phase 2: histogram of prob float-bits ----
    for (int i = tid; i < QC_; i += NT) {
        int q = (int)((u32)i / (u32)C_);
        float p = expf(lg[i] - rowmax[q]) / rowsum[q];
        atomicAdd(&hist[__float_as_uint(p) >> 19], 1u);
    }
    __syncthreads();

    // ---- Phase 3: hierarchical threshold-bin search (count(bins>T) < K <= count(bins>=T)) ----
    {
        u32 s = 0;
        int base = tid * (NBIN / NT);   // 8 bins/thread
        for (int k = 0; k < NBIN / NT; k++) s += hist[base + k];
        csum[tid] = s;
        u32 ws = s;
        for (int off = 32; off > 0; off >>= 1) ws += __shfl_xor(ws, off, 64);
        if ((tid & 63) == 0) swsum[tid >> 6] = ws;
    }
    __syncthreads();
    if (tid == 0) {
        u32 acc = 0;
        int w = 15;
        for (; w > 0; w--) { if (acc + swsum[w] >= (u32)K_) break; acc += swsum[w]; }
        int t = w * 64 + 63;
        for (; t > w * 64; t--) { if (acc + csum[t] >= (u32)K_) break; acc += csum[t]; }
        int bn = t * 8 + 7;
        for (; bn > t * 8; bn--) { if (acc + hist[bn] >= (u32)K_) break; acc += hist[bn]; }
        sT = bn;
    }
    __syncthreads();
    const int T = sT;
    __syncthreads();   // hist reads done; cand may alias it now

    // ---- Phase 4: collect candidate keys (bits<<32)|~i for bins >= T ----
    for (int i = tid; i < QC_; i += NT) {
        int q = (int)((u32)i / (u32)C_);
        float p = expf(lg[i] - rowmax[q]) / rowsum[q];   // bit-identical to phase 2
        u32 bits = __float_as_uint(p);
        if ((int)(bits >> 19) >= T) {
            u32 pos = atomicAdd(&s_cnt, 1u);
            if (pos < (u32)CAP)
                cand[pos] = ((u64)bits << 32) | (u32)(~i);
        }
    }
    __syncthreads();
    const int ncand_raw = (int)s_cnt;

    if (ncand_raw <= CAP) {
        // ---- Phase 5a: pad + bitonic sort (ascending), take top-100 from the end ----
        for (int e = tid; e < CAP; e += NT)
            if (e >= ncand_raw) cand[e] = 0;
        __syncthreads();
        for (int k = 2; k <= CAP; k <<= 1) {
            for (int j = k >> 1; j > 0; j >>= 1) {
                int e = tid;
                int partner = e ^ j;
                if (partner > e) {
                    u64 a = cand[e], bb = cand[partner];
                    bool up = ((e & k) == 0);
                    if ((a > bb) == up) { cand[e] = bb; cand[partner] = a; }
                }
                __syncthreads();
            }
        }
        if (tid < K_) {
            u64 m = cand[CAP - 1 - tid];
            u32 idx = ~(u32)m;
            sel_val[tid] = __uint_as_float((u32)(m >> 32));
            sel_q[tid]   = (int)(idx / (u32)C_);
            sel_lab[tid] = (int)(idx % (u32)C_);
        }
    } else {
        // ---- Phase 5b (near-dead fallback): 100-round argmax with strict-less chaining ----
        if (tid == 0) s_prev = ~0ull;
        __syncthreads();
        for (int r = 0; r < K_; r++) {
            u64 prev = s_prev;
            u64 local = 0;
            for (int i = tid; i < QC_; i += NT) {
                int q = (int)((u32)i / (u32)C_);
                float p = expf(lg[i] - rowmax[q]) / rowsum[q];
                u64 key = ((u64)__float_as_uint(p) << 32) | (u32)(~i);
                if (key < prev && key > local) local = key;
            }
            for (int off = 32; off > 0; off >>= 1) {
                u64 o = shfl_xor_u64(local, off);
                if (o > local) local = o;
            }
            if ((tid & 63) == 0) wred[tid >> 6] = local;
            __syncthreads();
            if (tid == 0) {
                u64 m = wred[0];
                for (int wv = 1; wv < 16; wv++) if (wred[wv] > m) m = wred[wv];
                s_prev = m;
                u32 idx = ~(u32)m;
                if (idx >= (u32)QC_) idx = 0;
                sel_val[r] = __uint_as_float((u32)(m >> 32));
                sel_q[r]   = (int)(idx / (u32)C_);
                sel_lab[r] = (int)(idx % (u32)C_);
            }
            __syncthreads();
        }
    }
    __syncthreads();   // sel_* visible; cand/hist/rowmax/rowsum all dead

    // ---- Phase 5.5: gather + scale boxes; init maxbits + suprow ----
    if (tid < K_) {
        int r = tid;
        int q = sel_q[r];
        float iw = (float)tsizes[b * 2 + 1];
        float ih = (float)tsizes[b * 2 + 0];
        const float* sb = sub_boxes_in + ((size_t)b * Q_ + q) * 4;
        const float* ob = obj_boxes_in + ((size_t)b * Q_ + q) * 4;
        float cx = sb[0], cy = sb[1], bw = sb[2], bh = sb[3];
        bsub[r][0] = (cx - 0.5f * bw) * iw; bsub[r][1] = (cy - 0.5f * bh) * ih;
        bsub[r][2] = (cx + 0.5f * bw) * iw; bsub[r][3] = (cy + 0.5f * bh) * ih;
        cx = ob[0]; cy = ob[1]; bw = ob[2]; bh = ob[3];
        bobj[r][0] = (cx - 0.5f * bw) * iw; bobj[r][1] = (cy - 0.5f * bh) * ih;
        bobj[r][2] = (cx + 0.5f * bw) * iw; bobj[r][3] = (cy + 0.5f * bh) * ih;
        maxbits[r] = 0;
        suprow[r][0] = 0; suprow[r][1] = 0; suprow[r][2] = 0; suprow[r][3] = 0;
    }
    __syncthreads();

    // ---- Phase 6: hoi scores into hs (reuses sbuf); per-row max via atomicMax ----
    for (int f = tid; f < KV_; f += NT) {
        int r = f / V_, v = f - r * V_;
        int q = sel_q[r];
        float x = verb_logits[((size_t)b * Q_ + q) * V_ + v];
        float s = 1.f / (1.f + expf(-x));
        float hval = s * sel_val[r] * cm[v * C_ + sel_lab[r]];
        hs[f] = hval;
        atomicMax(&maxbits[r], __float_as_int(hval));   // hval >= 0: int-bits monotone
    }
    __syncthreads();

    // ---- Phase 7: stable descending rank of max scores ----
    if (tid < K_) {
        int r = tid;
        u64 kr = ((u64)(u32)maxbits[r] << 32) | (u32)(~r);
        int rank = 0;
        for (int j = 0; j < K_; j++) {
            u64 kj = ((u64)(u32)maxbits[j] << 32) | (u32)(~j);
            rank += (kj > kr) ? 1 : 0;
        }
        order_[rank] = r;
    }
    __syncthreads();

    // ---- Phase 8a: build 100x100 suppression bitmatrix in sorted space ----
    for (int e = tid; e < K_ * K_; e += NT) {
        int i = e / K_, j = e - i * K_;
        if (j > i) {
            int ri = order_[i], rj = order_[j];
            if (sel_lab[ri] == sel_lab[rj]) {
                float o = iou1(bsub[ri], bsub[rj]) * iou1(bobj[ri], bobj[rj]);
                if (o > 0.5f)
                    atomicOr(&suprow[i][j >> 5], 1u << (j & 31));
            }
        }
    }
    __syncthreads();

    // ---- Phase 8b: greedy scan — single wave, register-resident, zero barriers ----
    if (tid < 64) {
        u32 ra0 = suprow[tid][0], ra1 = suprow[tid][1], ra2 = suprow[tid][2], ra3 = suprow[tid][3];
        u32 rb0 = 0, rb1 = 0, rb2 = 0, rb3 = 0;
        if (tid < K_ - 64) {
            rb0 = suprow[tid + 64][0]; rb1 = suprow[tid + 64][1];
            rb2 = suprow[tid + 64][2]; rb3 = suprow[tid + 64][3];
        }
        u32 acc[4] = {0, 0, 0, 0};
        u32 km[4]  = {0, 0, 0, 0};
        #pragma unroll
        for (int i = 0; i < K_; i++) {
            u32 r0, r1, r2, r3;
            if (i < 64) {
                r0 = (u32)__shfl((int)ra0, i, 64); r1 = (u32)__shfl((int)ra1, i, 64);
                r2 = (u32)__shfl((int)ra2, i, 64); r3 = (u32)__shfl((int)ra3, i, 64);
            } else {
                r0 = (u32)__shfl((int)rb0, i - 64, 64); r1 = (u32)__shfl((int)rb1, i - 64, 64);
                r2 = (u32)__shfl((int)rb2, i - 64, 64); r3 = (u32)__shfl((int)rb3, i - 64, 64);
            }
            bool sup_i = (acc[i >> 5] >> (i & 31)) & 1u;
            if (!sup_i) {
                km[i >> 5] |= 1u << (i & 31);
                acc[0] |= r0; acc[1] |= r1; acc[2] |= r2; acc[3] |= r3;
            }
        }
        if (tid == 0) { skeep[0] = km[0]; skeep[1] = km[1]; skeep[2] = km[2]; skeep[3] = km[3]; }
    }
    __syncthreads();
    if (tid < K_)
        keep_un[order_[tid]] = (int)((skeep[tid >> 5] >> (tid & 31)) & 1u);
    __syncthreads();

    // ---- Phase 9: write outputs (float32, concatenated in return order) ----
    float* o0 = out;                                   // final_scores B,K,V
    float* o1 = out + (size_t)B_ * KV_;                // topk_values  B,K
    float* o2 = o1 + (size_t)B_ * K_;                  // obj_labels   B,K
    float* o3 = o2 + (size_t)B_ * K_;                  // sub_boxes    B,K,4
    float* o4 = o3 + (size_t)B_ * K_ * 4;              // obj_boxes    B,K,4
    float* o5 = o4 + (size_t)B_ * K_ * 4;              // keep         B,K

    for (int f = tid; f < KV_; f += NT) {
        int r = f / V_;
        float v = keep_un[r] ? hs[f] : 0.f;
        o0[(size_t)b * KV_ + f] = v;
    }
    if (tid < K_) {
        int r = tid;
        o1[(size_t)b * K_ + r] = sel_val[r];
        o2[(size_t)b * K_ + r] = (float)sel_lab[r];
        o5[(size_t)b * K_ + r] = keep_un[r] ? 1.f : 0.f;
    }
    if (tid < K_ * 4) {
        int r = tid >> 2, k = tid & 3;
        o3[((size_t)b * K_) * 4 + tid] = bsub[r][k];
        o4[((size_t)b * K_) * 4 + tid] = bobj[r][k];
    }
}

extern "C" void kernel_launch(void* const* d_in, const int* in_sizes, int n_in,
                              void* d_out, int out_size, void* d_ws, size_t ws_size,
                              hipStream_t stream) {
    const float* obj_logits  = (const float*)d_in[0];
    const float* verb_logits = (const float*)d_in[1];
    const float* sub_boxes   = (const float*)d_in[2];
    const float* obj_boxes   = (const float*)d_in[3];
    const float* cm          = (const float*)d_in[4];
    const int*   ts          = (const int*)d_in[5];
    hipLaunchKernelGGL(hoi_kernel, dim3(B_), dim3(NT), 0, stream,
                       obj_logits, verb_logits, sub_boxes, obj_boxes, cm, ts,
                       (float*)d_out);
}

// Round 4
// 148.578 us; speedup vs baseline: 2.2692x; 1.0852x over previous
//
#include <hip/hip_runtime.h>
#include <cmath>

#pragma clang fp contract(off)

#define NT 1024
constexpr int B_ = 256, Q_ = 300, C_ = 81, V_ = 117, K_ = 100;
constexpr int QC_ = Q_ * C_;   // 24300
constexpr int KV_ = K_ * V_;   // 11700
constexpr int NB  = 2048;      // histogram bins = prob float-bits >> 21
constexpr int CAP = 1024;      // LDS candidate buffer (fallback sort size)

using u32 = unsigned int;
using u64 = unsigned long long;
using u16 = unsigned short;
using u8  = unsigned char;

// ---- LDS layout (lifetime-aliased, hand-packed; 65,344 B <= 64 KiB) ----
constexpr int OFF_P16  = 0;                 // u16[24300]=48600 | hs f32[11700]=46800 (phase>=6)
constexpr int OFF_HIST = 48600;             // u32[2048]=8192   | cand u64[1024] (after threshold)
constexpr int OFF_RMAX = OFF_HIST + 8192;   // f32[300]
constexpr int OFF_RSUM = OFF_RMAX + 1200;   // f32[300]
constexpr int OFF_BSUB = OFF_RSUM + 1200;   // f32[100][4] | swsum u32[16] (phase 3)
constexpr int OFF_BOBJ = OFF_BSUB + 1600;   // f32[100][4] | wred u64[16] (fallback 5b)
constexpr int OFF_SUPR = OFF_BOBJ + 1600;   // u32[100][4] | s_prev u64 (fallback 5b)
constexpr int OFF_SELV = OFF_SUPR + 1600;   // f32[100]
constexpr int OFF_SELI = OFF_SELV + 400;    // u32[100] flat topk index
constexpr int OFF_MAXB = OFF_SELI + 400;    // i32[100]
constexpr int OFF_ORD  = OFF_MAXB + 400;    // u8[100] (pad 104)
constexpr int OFF_MISC = OFF_ORD + 104;     // skeep[4], keep_bits[4], s_cnt, sT, sW, sAcc
constexpr int SMEM_SZ  = OFF_MISC + 48;     // 65,344
static_assert(SMEM_SZ <= 65536, "LDS overflow");

__device__ __forceinline__ u64 shfl_xor_u64(u64 v, int mask) {
    u32 lo = (u32)v, hi = (u32)(v >> 32);
    lo = (u32)__shfl_xor((int)lo, mask, 64);
    hi = (u32)__shfl_xor((int)hi, mask, 64);
    return ((u64)hi << 32) | lo;
}

__device__ __forceinline__ float iou1(const float* a, const float* b) {
    float areaA = (a[2] - a[0] + 1.f) * (a[3] - a[1] + 1.f);
    float areaB = (b[2] - b[0] + 1.f) * (b[3] - b[1] + 1.f);
    float xx1 = fmaxf(a[0], b[0]);
    float yy1 = fmaxf(a[1], b[1]);
    float xx2 = fminf(a[2], b[2]);
    float yy2 = fminf(a[3], b[3]);
    float w = fmaxf(0.f, xx2 - xx1 + 1.f);
    float h = fmaxf(0.f, yy2 - yy1 + 1.f);
    float inter = w * h;
    return inter / (areaA + areaB - inter);
}

__global__ __launch_bounds__(NT) void hoi_kernel(
    const float* __restrict__ obj_logits,   // B,Q,C
    const float* __restrict__ verb_logits,  // B,Q,V
    const float* __restrict__ sub_boxes_in, // B,Q,4
    const float* __restrict__ obj_boxes_in, // B,Q,4
    const float* __restrict__ cm,           // V,C
    const int*   __restrict__ tsizes,       // B,2 (h,w)
    float* __restrict__ out)
{
    const int b = blockIdx.x;
    const int tid = threadIdx.x;

    __shared__ __align__(16) u8 smem[SMEM_SZ];
    u16*   p16     = (u16*)(smem + OFF_P16);
    float* hs      = (float*)(smem + OFF_P16);
    u32*   hist    = (u32*)(smem + OFF_HIST);
    u64*   cand    = (u64*)(smem + OFF_HIST);
    float* rowmax  = (float*)(smem + OFF_RMAX);
    float* rowsum  = (float*)(smem + OFF_RSUM);
    float (*bsub)[4]   = (float(*)[4])(smem + OFF_BSUB);
    float (*bobj)[4]   = (float(*)[4])(smem + OFF_BOBJ);
    u32   (*suprow)[4] = (u32(*)[4])(smem + OFF_SUPR);
    float* sel_val = (float*)(smem + OFF_SELV);
    u32*   sel_idx = (u32*)(smem + OFF_SELI);
    int*   maxbits = (int*)(smem + OFF_MAXB);
    u8*    order8  = (u8*)(smem + OFF_ORD);
    u32*   skeep     = (u32*)(smem + OFF_MISC);
    u32*   keep_bits = (u32*)(smem + OFF_MISC + 16);
    u32*   s_cnt     = (u32*)(smem + OFF_MISC + 32);
    int*   sT        = (int*)(smem + OFF_MISC + 36);
    int*   sW        = (int*)(smem + OFF_MISC + 40);
    u32*   sAcc      = (u32*)(smem + OFF_MISC + 44);
    u32*   swsum   = (u32*)(smem + OFF_BSUB);   // phase-3 scratch
    u64*   wred    = (u64*)(smem + OFF_BOBJ);   // 5b scratch
    u64*   s_prev  = (u64*)(smem + OFF_SUPR);   // 5b scratch

    const float* lg = obj_logits + (size_t)b * QC_;

    for (int i = tid; i < NB; i += NT) hist[i] = 0;
    if (tid == 0) *s_cnt = 0;
    __syncthreads();

    // ---- Phase 1 (fused): ONE pass over logits -> softmax, p16 cache, histogram, rowstats ----
    {
        int g = tid >> 5, l = tid & 31;
        bool have2 = (l < C_ - 64);   // l < 17
        for (int q = g; q < Q_; q += 32) {
            const float* row = lg + q * C_;
            float v0 = row[l], v1 = row[l + 32];
            float v2 = have2 ? row[l + 64] : -INFINITY;
            float m = fmaxf(fmaxf(v0, v1), v2);
            for (int off = 16; off; off >>= 1) m = fmaxf(m, __shfl_xor(m, off, 64));
            float e0 = expf(v0 - m), e1 = expf(v1 - m);
            float e2 = have2 ? expf(v2 - m) : 0.f;
            float s = e0 + e1 + e2;
            for (int off = 16; off; off >>= 1) s += __shfl_xor(s, off, 64);
            float p0 = e0 / s, p1 = e1 / s;
            u32 b0 = __float_as_uint(p0), b1 = __float_as_uint(p1);
            p16[q * C_ + l]      = (u16)(b0 >> 16);
            p16[q * C_ + l + 32] = (u16)(b1 >> 16);
            atomicAdd(&hist[b0 >> 21], 1u);
            atomicAdd(&hist[b1 >> 21], 1u);
            if (have2) {
                float p2 = e2 / s;
                u32 b2 = __float_as_uint(p2);
                p16[q * C_ + l + 64] = (u16)(b2 >> 16);
                atomicAdd(&hist[b2 >> 21], 1u);
            }
            if (l == 0) { rowmax[q] = m; rowsum[q] = s; }
        }
    }
    __syncthreads();

    // ---- Phase 3: threshold bin T via two-level shfl suffix-scan (no serial scan) ----
    u32 my_c, my_suf;
    {
        int t = tid;
        my_c = hist[2 * t] + hist[2 * t + 1];
        my_suf = my_c;
        #pragma unroll
        for (int off = 1; off < 64; off <<= 1) {
            u32 o = (u32)__shfl_down((int)my_suf, off, 64);
            my_suf += ((tid & 63) + off < 64) ? o : 0;
        }
        if ((tid & 63) == 0) swsum[tid >> 6] = my_suf;
    }
    __syncthreads();
    if (tid < 16) {
        u32 sufW = swsum[tid];
        #pragma unroll
        for (int off = 1; off < 16; off <<= 1) {
            u32 o = (u32)__shfl_down((int)sufW, off, 64);
            sufW += (tid + off < 16) ? o : 0;
        }
        u32 nxt = (u32)__shfl_down((int)sufW, 1, 64);
        if (tid == 15) nxt = 0;
        if (sufW >= (u32)K_ && nxt < (u32)K_) { *sW = tid; *sAcc = nxt; }
    }
    __syncthreads();
    if ((tid >> 6) == *sW) {
        u32 above = *sAcc + (my_suf - my_c);                 // count in bins above my 2-bin chunk
        if (above < (u32)K_ && above + my_c >= (u32)K_) {
            u32 acc = above + hist[2 * tid + 1];
            *sT = (acc >= (u32)K_) ? (2 * tid + 1) : (2 * tid);
        }
    }
    __syncthreads();
    const int T = *sT;
    __syncthreads();   // hist reads done; cand may alias

    // ---- Phase 4: scan p16 cache; exact keys recomputed only for candidates ----
    for (int i = tid; i < QC_; i += NT) {
        u32 pb = p16[i];
        if ((int)(pb >> 5) >= T) {
            u32 pos = atomicAdd(s_cnt, 1u);
            if (pos < (u32)CAP) {
                int q = i / C_;
                float p = expf(lg[i] - rowmax[q]) / rowsum[q];  // bit-identical to phase 1
                cand[pos] = ((u64)__float_as_uint(p) << 32) | (u32)(~i);
            }
        }
    }
    __syncthreads();
    const int ncand = (int)*s_cnt;

    auto cswap = [](u64& a, u64& bb, bool up) {
        if ((a > bb) == up) { u64 t = a; a = bb; bb = t; }
    };

    if (ncand <= 256) {
        // ---- Phase 5a: register-resident bitonic-256 on wave 0 — ZERO barriers ----
        if (tid < 64) {
            u64 v0 = (tid < ncand) ? cand[tid] : 0ull;
            u64 v1 = (64 + tid < ncand) ? cand[64 + tid] : 0ull;
            u64 v2 = (128 + tid < ncand) ? cand[128 + tid] : 0ull;
            u64 v3 = (192 + tid < ncand) ? cand[192 + tid] : 0ull;
            for (int k = 2; k <= 256; k <<= 1) {
                for (int j = k >> 1; j > 0; j >>= 1) {
                    if (j == 128) {            // k==256: pairs (v0,v2),(v1,v3), ascending
                        cswap(v0, v2, true);
                        cswap(v1, v3, true);
                    } else if (j == 64) {      // pairs (v0,v1),(v2,v3)
                        cswap(v0, v1, true);
                        cswap(v2, v3, (k == 256));
                    } else {
                        auto step = [&](u64& v, int ebase) {
                            u64 pv = shfl_xor_u64(v, j);
                            int e = ebase + tid;
                            bool up = ((e & k) == 0);
                            bool lower = ((e & j) == 0);
                            u64 mn = v < pv ? v : pv;
                            u64 mx = v < pv ? pv : v;
                            v = (lower == up) ? mn : mx;
                        };
                        step(v0, 0); step(v1, 64); step(v2, 128); step(v3, 192);
                    }
                }
            }
            // ascending: rank t = element 255-t; top-100 in e >= 156
            int e2 = 128 + tid;
            if (e2 >= 156) {
                int t = 255 - e2;
                sel_val[t] = __uint_as_float((u32)(v2 >> 32));
                sel_idx[t] = ~(u32)v2;
            }
            int t3 = 255 - (192 + tid);   // in [0,63]
            sel_val[t3] = __uint_as_float((u32)(v3 >> 32));
            sel_idx[t3] = ~(u32)v3;
        }
    } else if (ncand <= CAP) {
        // ---- Phase 5b: LDS bitonic-1024 fallback ----
        for (int e = tid; e < CAP; e += NT)
            if (e >= ncand) cand[e] = 0;
        __syncthreads();
        for (int k = 2; k <= CAP; k <<= 1) {
            for (int j = k >> 1; j > 0; j >>= 1) {
                int e = tid, partner = e ^ j;
                if (partner > e) {
                    u64 a = cand[e], bb = cand[partner];
                    bool up = ((e & k) == 0);
                    if ((a > bb) == up) { cand[e] = bb; cand[partner] = a; }
                }
                __syncthreads();
            }
        }
        if (tid < K_) {
            u64 m = cand[CAP - 1 - tid];
            sel_val[tid] = __uint_as_float((u32)(m >> 32));
            sel_idx[tid] = ~(u32)m;
        }
    } else {
        // ---- Phase 5c (near-dead): 100-round argmax over QC with strict-less chaining ----
        if (tid == 0) *s_prev = ~0ull;
        __syncthreads();
        for (int r = 0; r < K_; r++) {
            u64 prev = *s_prev;
            u64 local = 0;
            for (int i = tid; i < QC_; i += NT) {
                int q = i / C_;
                float p = expf(lg[i] - rowmax[q]) / rowsum[q];
                u64 key = ((u64)__float_as_uint(p) << 32) | (u32)(~i);
                if (key < prev && key > local) local = key;
            }
            for (int off = 32; off > 0; off >>= 1) {
                u64 o = shfl_xor_u64(local, off);
                if (o > local) local = o;
            }
            if ((tid & 63) == 0) wred[tid >> 6] = local;
            __syncthreads();
            if (tid == 0) {
                u64 m = wred[0];
                for (int wv = 1; wv < 16; wv++) if (wred[wv] > m) m = wred[wv];
                *s_prev = m;
                u32 idx = ~(u32)m;
                if (idx >= (u32)QC_) idx = 0;
                sel_val[r] = __uint_as_float((u32)(m >> 32));
                sel_idx[r] = idx;
            }
            __syncthreads();
        }
    }
    __syncthreads();   // sel_* visible; p16/hist/cand/rowstats dead

    // ---- Phase 5.5: gather + scale boxes; init NMS state ----
    if (tid < K_) {
        int idx = (int)sel_idx[tid];
        int q = idx / C_;
        float iw = (float)tsizes[b * 2 + 1];
        float ih = (float)tsizes[b * 2 + 0];
        float4 sb = ((const float4*)sub_boxes_in)[(size_t)b * Q_ + q];
        float4 ob = ((const float4*)obj_boxes_in)[(size_t)b * Q_ + q];
        bsub[tid][0] = (sb.x - 0.5f * sb.z) * iw; bsub[tid][1] = (sb.y - 0.5f * sb.w) * ih;
        bsub[tid][2] = (sb.x + 0.5f * sb.z) * iw; bsub[tid][3] = (sb.y + 0.5f * sb.w) * ih;
        bobj[tid][0] = (ob.x - 0.5f * ob.z) * iw; bobj[tid][1] = (ob.y - 0.5f * ob.w) * ih;
        bobj[tid][2] = (ob.x + 0.5f * ob.z) * iw; bobj[tid][3] = (ob.y + 0.5f * ob.w) * ih;
        maxbits[tid] = 0;
        suprow[tid][0] = 0; suprow[tid][1] = 0; suprow[tid][2] = 0; suprow[tid][3] = 0;
    }
    if (tid >= 128 && tid < 132) keep_bits[tid - 128] = 0;
    __syncthreads();

    // ---- Phase 6: hoi scores into hs; per-row max via atomicMax ----
    for (int f = tid; f < KV_; f += NT) {
        int r = f / V_, v = f - r * V_;
        int idx = (int)sel_idx[r];
        int q = idx / C_, lab = idx - q * C_;
        float x = verb_logits[((size_t)b * Q_ + q) * V_ + v];
        float s = 1.f / (1.f + expf(-x));
        float hval = s * sel_val[r] * cm[v * C_ + lab];
        hs[f] = hval;
        atomicMax(&maxbits[r], __float_as_int(hval));   // hval >= 0: bits monotone
    }
    __syncthreads();

    // ---- Phase 7: stable descending rank of max scores ----
    if (tid < K_) {
        int r = tid;
        u64 kr = ((u64)(u32)maxbits[r] << 32) | (u32)(~r);
        int rank = 0;
        for (int j = 0; j < K_; j++) {
            u64 kj = ((u64)(u32)maxbits[j] << 32) | (u32)(~j);
            rank += (kj > kr) ? 1 : 0;
        }
        order8[rank] = (u8)r;
    }
    __syncthreads();

    // ---- Phase 8a: 100x100 suppression bitmatrix in sorted space ----
    for (int e = tid; e < K_ * K_; e += NT) {
        int i = e / K_, j = e - i * K_;
        if (j > i) {
            int ri = order8[i], rj = order8[j];
            u32 li = sel_idx[ri] % (u32)C_, lj = sel_idx[rj] % (u32)C_;
            if (li == lj) {
                float o = iou1(bsub[ri], bsub[rj]) * iou1(bobj[ri], bobj[rj]);
                if (o > 0.5f)
                    atomicOr(&suprow[i][j >> 5], 1u << (j & 31));
            }
        }
    }
    __syncthreads();

    // ---- Phase 8b: greedy scan — single wave, register-resident, zero barriers ----
    if (tid < 64) {
        u32 ra0 = suprow[tid][0], ra1 = suprow[tid][1], ra2 = suprow[tid][2], ra3 = suprow[tid][3];
        u32 rb0 = 0, rb1 = 0, rb2 = 0, rb3 = 0;
        if (tid < K_ - 64) {
            rb0 = suprow[tid + 64][0]; rb1 = suprow[tid + 64][1];
            rb2 = suprow[tid + 64][2]; rb3 = suprow[tid + 64][3];
        }
        u32 acc[4] = {0, 0, 0, 0};
        u32 km[4]  = {0, 0, 0, 0};
        #pragma unroll
        for (int i = 0; i < K_; i++) {
            u32 r0, r1, r2, r3;
            if (i < 64) {
                r0 = (u32)__shfl((int)ra0, i, 64); r1 = (u32)__shfl((int)ra1, i, 64);
                r2 = (u32)__shfl((int)ra2, i, 64); r3 = (u32)__shfl((int)ra3, i, 64);
            } else {
                r0 = (u32)__shfl((int)rb0, i - 64, 64); r1 = (u32)__shfl((int)rb1, i - 64, 64);
                r2 = (u32)__shfl((int)rb2, i - 64, 64); r3 = (u32)__shfl((int)rb3, i - 64, 64);
            }
            bool sup_i = (acc[i >> 5] >> (i & 31)) & 1u;
            if (!sup_i) {
                km[i >> 5] |= 1u << (i & 31);
                acc[0] |= r0; acc[1] |= r1; acc[2] |= r2; acc[3] |= r3;
            }
        }
        if (tid == 0) { skeep[0] = km[0]; skeep[1] = km[1]; skeep[2] = km[2]; skeep[3] = km[3]; }
    }
    __syncthreads();
    if (tid < K_) {
        if ((skeep[tid >> 5] >> (tid & 31)) & 1u) {
            int r = order8[tid];
            atomicOr(&keep_bits[r >> 5], 1u << (r & 31));
        }
    }
    __syncthreads();

    // ---- Phase 9: write outputs (float32, concatenated in return order) ----
    float* o0 = out;                                   // final_scores B,K,V
    float* o1 = out + (size_t)B_ * KV_;                // topk_values  B,K
    float* o2 = o1 + (size_t)B_ * K_;                  // obj_labels   B,K
    float* o3 = o2 + (size_t)B_ * K_;                  // sub_boxes    B,K,4
    float* o4 = o3 + (size_t)B_ * K_ * 4;              // obj_boxes    B,K,4
    float* o5 = o4 + (size_t)B_ * K_ * 4;              // keep         B,K

    for (int f = tid; f < KV_; f += NT) {
        int r = f / V_;
        bool kp = (keep_bits[r >> 5] >> (r & 31)) & 1u;
        o0[(size_t)b * KV_ + f] = kp ? hs[f] : 0.f;
    }
    if (tid < K_) {
        bool kp = (keep_bits[tid >> 5] >> (tid & 31)) & 1u;
        o1[(size_t)b * K_ + tid] = sel_val[tid];
        o2[(size_t)b * K_ + tid] = (float)(sel_idx[tid] % (u32)C_);
        o5[(size_t)b * K_ + tid] = kp ? 1.f : 0.f;
    }
    if (tid < K_ * 4) {
        int r = tid >> 2, k = tid & 3;
        o3[((size_t)b * K_) * 4 + tid] = bsub[r][k];
        o4[((size_t)b * K_) * 4 + tid] = bobj[r][k];
    }
}

extern "C" void kernel_launch(void* const* d_in, const int* in_sizes, int n_in,
                              void* d_out, int out_size, void* d_ws, size_t ws_size,
                              hipStream_t stream) {
    const float* obj_logits  = (const float*)d_in[0];
    const float* verb_logits = (const float*)d_in[1];
    const float* sub_boxes   = (const float*)d_in[2];
    const float* obj_boxes   = (const float*)d_in[3];
    const float* cm          = (const float*)d_in[4];
    const int*   ts          = (const int*)d_in[5];
    hipLaunchKernelGGL(hoi_kernel, dim3(B_), dim3(NT), 0, stream,
                       obj_logits, verb_logits, sub_boxes, obj_boxes, cm, ts,
                       (float*)d_out);
}

// Round 5
// 143.131 us; speedup vs baseline: 2.3556x; 1.0381x over previous
//
#include <hip/hip_runtime.h>
#include <cmath>

#pragma clang fp contract(off)

#define NT 1024
constexpr int B_ = 256, Q_ = 300, C_ = 81, V_ = 117, K_ = 100;
constexpr int QC_ = Q_ * C_;   // 24300
constexpr int KV_ = K_ * V_;   // 11700
constexpr int NB  = 2048;      // histogram bins = prob float-bits >> 21
constexpr int CAP = 1024;      // LDS candidate buffer (fallback sort size)

using u32 = unsigned int;
using u64 = unsigned long long;
using u16 = unsigned short;
using u8  = unsigned char;

// ---- LDS layout (lifetime-aliased, hand-packed; 65,344 B <= 64 KiB) ----
constexpr int OFF_P16  = 0;                 // u16[24300]=48600 | hs f32[11700]=46800 (phase>=6)
constexpr int OFF_HIST = 48600;             // u32[2048]=8192   | cand u64[1024] (after threshold)
constexpr int OFF_RMAX = OFF_HIST + 8192;   // f32[300]
constexpr int OFF_RINV = OFF_RMAX + 1200;   // f32[300] per-row 1/sum
constexpr int OFF_BSUB = OFF_RINV + 1200;   // f32[100][4] | swsum u32[16] (phase 3)
constexpr int OFF_BOBJ = OFF_BSUB + 1600;   // f32[100][4] | wred u64[16] (fallback 5c)
constexpr int OFF_SUPR = OFF_BOBJ + 1600;   // u32[100][4] | s_prev u64 (fallback 5c)
constexpr int OFF_SELV = OFF_SUPR + 1600;   // f32[100]
constexpr int OFF_SELI = OFF_SELV + 400;    // u32[100] flat topk index
constexpr int OFF_MAXB = OFF_SELI + 400;    // u32[100] row-max bits
constexpr int OFF_ORD  = OFF_MAXB + 400;    // u8[100] (pad 104)
constexpr int OFF_MISC = OFF_ORD + 104;     // skeep[4], keep_bits[4], s_cnt, sT, sW, sAcc
constexpr int SMEM_SZ  = OFF_MISC + 48;     // 65,344
static_assert(SMEM_SZ <= 65536, "LDS overflow");

__device__ __forceinline__ u64 shfl_xor_u64(u64 v, int mask) {
    u32 lo = (u32)v, hi = (u32)(v >> 32);
    lo = (u32)__shfl_xor((int)lo, mask, 64);
    hi = (u32)__shfl_xor((int)hi, mask, 64);
    return ((u64)hi << 32) | lo;
}

__device__ __forceinline__ float iou1(const float* a, const float* b) {
    float areaA = (a[2] - a[0] + 1.f) * (a[3] - a[1] + 1.f);
    float areaB = (b[2] - b[0] + 1.f) * (b[3] - b[1] + 1.f);
    float xx1 = fmaxf(a[0], b[0]);
    float yy1 = fmaxf(a[1], b[1]);
    float xx2 = fminf(a[2], b[2]);
    float yy2 = fminf(a[3], b[3]);
    float w = fmaxf(0.f, xx2 - xx1 + 1.f);
    float h = fmaxf(0.f, yy2 - yy1 + 1.f);
    float inter = w * h;
    return inter / (areaA + areaB - inter);
}

__global__ __launch_bounds__(NT) void hoi_kernel(
    const float* __restrict__ obj_logits,   // B,Q,C
    const float* __restrict__ verb_logits,  // B,Q,V
    const float* __restrict__ sub_boxes_in, // B,Q,4
    const float* __restrict__ obj_boxes_in, // B,Q,4
    const float* __restrict__ cm,           // V,C
    const int*   __restrict__ tsizes,       // B,2 (h,w)
    float* __restrict__ out)
{
    const int b = blockIdx.x;
    const int tid = threadIdx.x;

    __shared__ __align__(16) u8 smem[SMEM_SZ];
    u16*   p16     = (u16*)(smem + OFF_P16);
    float* hs      = (float*)(smem + OFF_P16);
    u32*   hist    = (u32*)(smem + OFF_HIST);
    u64*   cand    = (u64*)(smem + OFF_HIST);
    float* rowmax  = (float*)(smem + OFF_RMAX);
    float* rinv    = (float*)(smem + OFF_RINV);
    float (*bsub)[4]   = (float(*)[4])(smem + OFF_BSUB);
    float (*bobj)[4]   = (float(*)[4])(smem + OFF_BOBJ);
    u32   (*suprow)[4] = (u32(*)[4])(smem + OFF_SUPR);
    float* sel_val = (float*)(smem + OFF_SELV);
    u32*   sel_idx = (u32*)(smem + OFF_SELI);
    u32*   maxbits = (u32*)(smem + OFF_MAXB);
    u8*    order8  = (u8*)(smem + OFF_ORD);
    u32*   skeep     = (u32*)(smem + OFF_MISC);
    u32*   keep_bits = (u32*)(smem + OFF_MISC + 16);
    u32*   s_cnt     = (u32*)(smem + OFF_MISC + 32);
    int*   sT        = (int*)(smem + OFF_MISC + 36);
    int*   sW        = (int*)(smem + OFF_MISC + 40);
    u32*   sAcc      = (u32*)(smem + OFF_MISC + 44);
    u32*   swsum   = (u32*)(smem + OFF_BSUB);   // phase-3 scratch
    u64*   wred    = (u64*)(smem + OFF_BOBJ);   // 5c scratch
    u64*   s_prev  = (u64*)(smem + OFF_SUPR);   // 5c scratch

    const float* lg = obj_logits + (size_t)b * QC_;

    for (int i = tid; i < NB; i += NT) hist[i] = 0;
    if (tid == 0) *s_cnt = 0;
    __syncthreads();

    // ---- Phase 1 (fused): ONE pass over logits -> softmax, p16 cache, histogram ----
    // prob = exp(x - rowmax) * (1/rowsum): one div per ROW, not per element.
    {
        int g = tid >> 5, l = tid & 31;
        bool have2 = (l < C_ - 64);   // l < 17
        for (int q = g; q < Q_; q += 32) {
            const float* row = lg + q * C_;
            float v0 = row[l], v1 = row[l + 32];
            float v2 = have2 ? row[l + 64] : -INFINITY;
            float m = fmaxf(fmaxf(v0, v1), v2);
            for (int off = 16; off; off >>= 1) m = fmaxf(m, __shfl_xor(m, off, 64));
            float e0 = expf(v0 - m), e1 = expf(v1 - m);
            float e2 = have2 ? expf(v2 - m) : 0.f;
            float s = e0 + e1 + e2;
            for (int off = 16; off; off >>= 1) s += __shfl_xor(s, off, 64);
            float ri = 1.f / s;
            float p0 = e0 * ri, p1 = e1 * ri;
            u32 b0 = __float_as_uint(p0), b1 = __float_as_uint(p1);
            p16[q * C_ + l]      = (u16)(b0 >> 16);
            p16[q * C_ + l + 32] = (u16)(b1 >> 16);
            atomicAdd(&hist[b0 >> 21], 1u);
            atomicAdd(&hist[b1 >> 21], 1u);
            if (have2) {
                float p2 = e2 * ri;
                u32 b2 = __float_as_uint(p2);
                p16[q * C_ + l + 64] = (u16)(b2 >> 16);
                atomicAdd(&hist[b2 >> 21], 1u);
            }
            if (l == 0) { rowmax[q] = m; rinv[q] = ri; }
        }
    }
    __syncthreads();

    // ---- Phase 3: threshold bin T via two-level shfl suffix-scan ----
    u32 my_c, my_suf;
    {
        int t = tid;
        my_c = hist[2 * t] + hist[2 * t + 1];
        my_suf = my_c;
        #pragma unroll
        for (int off = 1; off < 64; off <<= 1) {
            u32 o = (u32)__shfl_down((int)my_suf, off, 64);
            my_suf += ((tid & 63) + off < 64) ? o : 0;
        }
        if ((tid & 63) == 0) swsum[tid >> 6] = my_suf;
    }
    __syncthreads();
    if (tid < 16) {
        u32 sufW = swsum[tid];
        #pragma unroll
        for (int off = 1; off < 16; off <<= 1) {
            u32 o = (u32)__shfl_down((int)sufW, off, 64);
            sufW += (tid + off < 16) ? o : 0;
        }
        u32 nxt = (u32)__shfl_down((int)sufW, 1, 64);
        if (tid == 15) nxt = 0;
        if (sufW >= (u32)K_ && nxt < (u32)K_) { *sW = tid; *sAcc = nxt; }
    }
    __syncthreads();
    if ((tid >> 6) == *sW) {
        u32 above = *sAcc + (my_suf - my_c);
        if (above < (u32)K_ && above + my_c >= (u32)K_) {
            u32 acc = above + hist[2 * tid + 1];
            *sT = (acc >= (u32)K_) ? (2 * tid + 1) : (2 * tid);
        }
    }
    __syncthreads();
    const int T = *sT;
    __syncthreads();   // hist reads done; cand may alias

    // ---- Phase 4: scan p16 cache; exact keys recomputed only for candidates ----
    for (int i = tid; i < QC_; i += NT) {
        u32 pb = p16[i];
        if ((int)(pb >> 5) >= T) {
            u32 pos = atomicAdd(s_cnt, 1u);
            if (pos < (u32)CAP) {
                int q = i / C_;
                float p = expf(lg[i] - rowmax[q]) * rinv[q];  // bit-identical to phase 1
                cand[pos] = ((u64)__float_as_uint(p) << 32) | (u32)(~i);
            }
        }
    }
    __syncthreads();
    const int ncand = (int)*s_cnt;

    auto cswap = [](u64& a, u64& bb, bool up) {
        if ((a > bb) == up) { u64 t = a; a = bb; bb = t; }
    };

    if (ncand <= 256) {
        // ---- Phase 5a: register-resident bitonic-256 on wave 0 — zero barriers ----
        if (tid < 64) {
            u64 v0 = (tid < ncand) ? cand[tid] : 0ull;
            u64 v1 = (64 + tid < ncand) ? cand[64 + tid] : 0ull;
            u64 v2 = (128 + tid < ncand) ? cand[128 + tid] : 0ull;
            u64 v3 = (192 + tid < ncand) ? cand[192 + tid] : 0ull;
            for (int k = 2; k <= 256; k <<= 1) {
                for (int j = k >> 1; j > 0; j >>= 1) {
                    if (j == 128) {
                        cswap(v0, v2, true);
                        cswap(v1, v3, true);
                    } else if (j == 64) {
                        cswap(v0, v1, true);
                        cswap(v2, v3, (k == 256));
                    } else {
                        auto step = [&](u64& v, int ebase) {
                            u64 pv = shfl_xor_u64(v, j);
                            int e = ebase + tid;
                            bool up = ((e & k) == 0);
                            bool lower = ((e & j) == 0);
                            u64 mn = v < pv ? v : pv;
                            u64 mx = v < pv ? pv : v;
                            v = (lower == up) ? mn : mx;
                        };
                        step(v0, 0); step(v1, 64); step(v2, 128); step(v3, 192);
                    }
                }
            }
            int e2 = 128 + tid;
            if (e2 >= 156) {
                int t = 255 - e2;
                sel_val[t] = __uint_as_float((u32)(v2 >> 32));
                sel_idx[t] = ~(u32)v2;
            }
            int t3 = 255 - (192 + tid);
            sel_val[t3] = __uint_as_float((u32)(v3 >> 32));
            sel_idx[t3] = ~(u32)v3;
        }
    } else if (ncand <= CAP) {
        // ---- Phase 5b: LDS bitonic-1024 fallback ----
        for (int e = tid; e < CAP; e += NT)
            if (e >= ncand) cand[e] = 0;
        __syncthreads();
        for (int k = 2; k <= CAP; k <<= 1) {
            for (int j = k >> 1; j > 0; j >>= 1) {
                int e = tid, partner = e ^ j;
                if (partner > e) {
                    u64 a = cand[e], bb = cand[partner];
                    bool up = ((e & k) == 0);
                    if ((a > bb) == up) { cand[e] = bb; cand[partner] = a; }
                }
                __syncthreads();
            }
        }
        if (tid < K_) {
            u64 m = cand[CAP - 1 - tid];
            sel_val[tid] = __uint_as_float((u32)(m >> 32));
            sel_idx[tid] = ~(u32)m;
        }
    } else {
        // ---- Phase 5c (near-dead): 100-round argmax with strict-less chaining ----
        if (tid == 0) *s_prev = ~0ull;
        __syncthreads();
        for (int r = 0; r < K_; r++) {
            u64 prev = *s_prev;
            u64 local = 0;
            for (int i = tid; i < QC_; i += NT) {
                int q = i / C_;
                float p = expf(lg[i] - rowmax[q]) * rinv[q];
                u64 key = ((u64)__float_as_uint(p) << 32) | (u32)(~i);
                if (key < prev && key > local) local = key;
            }
            for (int off = 32; off > 0; off >>= 1) {
                u64 o = shfl_xor_u64(local, off);
                if (o > local) local = o;
            }
            if ((tid & 63) == 0) wred[tid >> 6] = local;
            __syncthreads();
            if (tid == 0) {
                u64 m = wred[0];
                for (int wv = 1; wv < 16; wv++) if (wred[wv] > m) m = wred[wv];
                *s_prev = m;
                u32 idx = ~(u32)m;
                if (idx >= (u32)QC_) idx = 0;
                sel_val[r] = __uint_as_float((u32)(m >> 32));
                sel_idx[r] = idx;
            }
            __syncthreads();
        }
    }
    __syncthreads();   // sel_* visible; p16/hist/cand/rowstats dead

    // ---- Phase 5.5: gather + scale boxes; init NMS state ----
    if (tid < K_) {
        int idx = (int)sel_idx[tid];
        int q = idx / C_;
        float iw = (float)tsizes[b * 2 + 1];
        float ih = (float)tsizes[b * 2 + 0];
        float4 sb = ((const float4*)sub_boxes_in)[(size_t)b * Q_ + q];
        float4 ob = ((const float4*)obj_boxes_in)[(size_t)b * Q_ + q];
        bsub[tid][0] = (sb.x - 0.5f * sb.z) * iw; bsub[tid][1] = (sb.y - 0.5f * sb.w) * ih;
        bsub[tid][2] = (sb.x + 0.5f * sb.z) * iw; bsub[tid][3] = (sb.y + 0.5f * sb.w) * ih;
        bobj[tid][0] = (ob.x - 0.5f * ob.z) * iw; bobj[tid][1] = (ob.y - 0.5f * ob.w) * ih;
        bobj[tid][2] = (ob.x + 0.5f * ob.z) * iw; bobj[tid][3] = (ob.y + 0.5f * ob.w) * ih;
        suprow[tid][0] = 0; suprow[tid][1] = 0; suprow[tid][2] = 0; suprow[tid][3] = 0;
    }
    if (tid >= 128 && tid < 132) keep_bits[tid - 128] = 0;
    __syncthreads();

    // ---- Phase 6: hoi scores into hs (plain stores; NO same-address atomics) ----
    for (int f = tid; f < KV_; f += NT) {
        int r = f / V_, v = f - r * V_;
        int idx = (int)sel_idx[r];
        int q = idx / C_, lab = idx - q * C_;
        float x = verb_logits[((size_t)b * Q_ + q) * V_ + v];
        float s = 1.f / (1.f + expf(-x));
        hs[f] = s * sel_val[r] * cm[v * C_ + lab];
    }
    __syncthreads();

    // ---- Phase 6.5: per-row max, 8 lanes/row, shfl-reduce (replaces atomicMax) ----
    if (tid < 800) {
        int r = tid >> 3, j = tid & 7;
        float m = 0.f;   // hvals >= 0
        for (int k = 0; k < 15; k++) {
            int v = j * 15 + k;
            if (v < V_) m = fmaxf(m, hs[r * V_ + v]);
        }
        for (int off = 4; off; off >>= 1) m = fmaxf(m, __shfl_xor(m, off, 64));
        if (j == 0) maxbits[r] = __float_as_uint(m);
    }
    __syncthreads();

    // ---- Phase 7: stable descending rank, 8 lanes/row, shfl-sum ----
    if (tid < 800) {
        int r = tid >> 3, j = tid & 7;
        u64 kr = ((u64)maxbits[r] << 32) | (u32)(~r);
        int rank = 0;
        for (int k = 0; k < 13; k++) {
            int jj = j * 13 + k;
            if (jj < K_) {
                u64 kj = ((u64)maxbits[jj] << 32) | (u32)(~jj);
                rank += (kj > kr) ? 1 : 0;
            }
        }
        for (int off = 4; off; off >>= 1) rank += __shfl_xor(rank, off, 64);
        if (j == 0) order8[rank] = (u8)r;
    }
    __syncthreads();

    // ---- Phase 8a: 100x100 suppression bitmatrix in sorted space ----
    for (int e = tid; e < K_ * K_; e += NT) {
        int i = e / K_, j = e - i * K_;
        if (j > i) {
            int ri = order8[i], rj = order8[j];
            u32 li = sel_idx[ri] % (u32)C_, lj = sel_idx[rj] % (u32)C_;
            if (li == lj) {
                float o = iou1(bsub[ri], bsub[rj]) * iou1(bobj[ri], bobj[rj]);
                if (o > 0.5f)
                    atomicOr(&suprow[i][j >> 5], 1u << (j & 31));
            }
        }
    }
    __syncthreads();

    // ---- Phase 8b: greedy scan — single wave, register-resident, zero barriers ----
    if (tid < 64) {
        u32 ra0 = suprow[tid][0], ra1 = suprow[tid][1], ra2 = suprow[tid][2], ra3 = suprow[tid][3];
        u32 rb0 = 0, rb1 = 0, rb2 = 0, rb3 = 0;
        if (tid < K_ - 64) {
            rb0 = suprow[tid + 64][0]; rb1 = suprow[tid + 64][1];
            rb2 = suprow[tid + 64][2]; rb3 = suprow[tid + 64][3];
        }
        u32 acc[4] = {0, 0, 0, 0};
        u32 km[4]  = {0, 0, 0, 0};
        #pragma unroll
        for (int i = 0; i < K_; i++) {
            u32 r0, r1, r2, r3;
            if (i < 64) {
                r0 = (u32)__shfl((int)ra0, i, 64); r1 = (u32)__shfl((int)ra1, i, 64);
                r2 = (u32)__shfl((int)ra2, i, 64); r3 = (u32)__shfl((int)ra3, i, 64);
            } else {
                r0 = (u32)__shfl((int)rb0, i - 64, 64); r1 = (u32)__shfl((int)rb1, i - 64, 64);
                r2 = (u32)__shfl((int)rb2, i - 64, 64); r3 = (u32)__shfl((int)rb3, i - 64, 64);
            }
            bool sup_i = (acc[i >> 5] >> (i & 31)) & 1u;
            if (!sup_i) {
                km[i >> 5] |= 1u << (i & 31);
                acc[0] |= r0; acc[1] |= r1; acc[2] |= r2; acc[3] |= r3;
            }
        }
        if (tid == 0) { skeep[0] = km[0]; skeep[1] = km[1]; skeep[2] = km[2]; skeep[3] = km[3]; }
    }
    __syncthreads();
    if (tid < K_) {
        if ((skeep[tid >> 5] >> (tid & 31)) & 1u) {
            int r = order8[tid];
            atomicOr(&keep_bits[r >> 5], 1u << (r & 31));
        }
    }
    __syncthreads();

    // ---- Phase 9: write outputs (float32, concatenated in return order) ----
    float* o0 = out;                                   // final_scores B,K,V
    float* o1 = out + (size_t)B_ * KV_;                // topk_values  B,K
    float* o2 = o1 + (size_t)B_ * K_;                  // obj_labels   B,K
    float* o3 = o2 + (size_t)B_ * K_;                  // sub_boxes    B,K,4
    float* o4 = o3 + (size_t)B_ * K_ * 4;              // obj_boxes    B,K,4
    float* o5 = o4 + (size_t)B_ * K_ * 4;              // keep         B,K

    for (int f = tid; f < KV_; f += NT) {
        int r = f / V_;
        bool kp = (keep_bits[r >> 5] >> (r & 31)) & 1u;
        o0[(size_t)b * KV_ + f] = kp ? hs[f] : 0.f;
    }
    if (tid < K_) {
        bool kp = (keep_bits[tid >> 5] >> (tid & 31)) & 1u;
        o1[(size_t)b * K_ + tid] = sel_val[tid];
        o2[(size_t)b * K_ + tid] = (float)(sel_idx[tid] % (u32)C_);
        o5[(size_t)b * K_ + tid] = kp ? 1.f : 0.f;
    }
    if (tid < K_ * 4) {
        int r = tid >> 2, k = tid & 3;
        o3[((size_t)b * K_) * 4 + tid] = bsub[r][k];
        o4[((size_t)b * K_) * 4 + tid] = bobj[r][k];
    }
}

extern "C" void kernel_launch(void* const* d_in, const int* in_sizes, int n_in,
                              void* d_out, int out_size, void* d_ws, size_t ws_size,
                              hipStream_t stream) {
    const float* obj_logits  = (const float*)d_in[0];
    const float* verb_logits = (const float*)d_in[1];
    const float* sub_boxes   = (const float*)d_in[2];
    const float* obj_boxes   = (const float*)d_in[3];
    const float* cm          = (const float*)d_in[4];
    const int*   ts          = (const int*)d_in[5];
    hipLaunchKernelGGL(hoi_kernel, dim3(B_), dim3(NT), 0, stream,
                       obj_logits, verb_logits, sub_boxes, obj_boxes, cm, ts,
                       (float*)d_out);
}